// Round 10
// baseline (161.687 us; speedup 1.0000x reference)
//
#include <hip/hip_runtime.h>

// DilatedSpatialAttention — round 10: L3 pre-warm pass.
// DTYPES (established rounds 0-2): inputs fp32, output fp32.
// R7/R8/R9: three different conv structures all ~34-44us, BW pinned 1.1-1.9
// TB/s, FETCH ~= compulsory, VALU/conflicts low => constraint is external to
// the kernel. Theory: the harness's per-iteration 268MB d_ws poison (seen as
// 6.3TB/s fills) evicts all of L3 AFTER d_in restore -> conv's 9-tap dilated
// gather runs against cold HBM (~900cyc, page-unfriendly); streaming loads
// CAN do 6.3TB/s (m13). Fix: touch_kernel streams key_in+value+query (50MB,
// sequential uint4) to re-warm L3; conv gather then sees ~200cyc L2/L3.
// conv + attn BYTE-IDENTICAL to R9 => absmax must stay exactly 1.220703e-4.
// Signature to check: conv FETCH_SIZE 30.8MB -> <5MB (L3 hits aren't HBM).
#define B_    16
#define HH    32
#define WW    32
#define CC    256
#define HEADS 8
#define HD    32
#define S_    1024
#define KT    128                 // keys per LDS tile
#define NITER (S_ / KT)           // 8
#define SCALE_L2E 0.25503486f     // 32^-0.5 * log2(e)  (pre-folded into Kws)

typedef unsigned short u16;
typedef unsigned int   u32;
typedef __attribute__((ext_vector_type(8))) short short8;  // 8 bf16 (A/B frag)
typedef __attribute__((ext_vector_type(4))) float f32x4;   // C/D frag

__device__ __forceinline__ u16 f2bf(float f) {             // RNE
    u32 x = __float_as_uint(f);
    return (u16)((x + 0x7fffu + ((x >> 16) & 1u)) >> 16);
}
__device__ __forceinline__ u32 pack2bf(float lo, float hi) {
    return (u32)f2bf(lo) | ((u32)f2bf(hi) << 16);
}

// ---------------------------------------------------------------------------
// Kernel 0: L3 pre-warm. Streams the three 16.8MB input tensors sequentially
// (the access pattern that reaches ~6.3TB/s) so the conv gather hits L3.
// XOR-sink per thread into an unused d_ws region prevents DCE.
// ---------------------------------------------------------------------------
__global__ __launch_bounds__(256) void touch_kernel(
    const uint4* __restrict__ a, const uint4* __restrict__ b,
    const uint4* __restrict__ c, u32* __restrict__ sink)
{
    const size_t N = (size_t)B_ * HH * WW * CC / 4;   // 1048576 uint4 per tensor
    size_t i = blockIdx.x * 256 + threadIdx.x;        // 262144 threads
    u32 acc = 0;
    #pragma unroll
    for (int t = 0; t < 4; t++, i += 262144) {
        uint4 x = a[i]; acc ^= x.x ^ x.y ^ x.z ^ x.w;
        uint4 y = b[i]; acc ^= y.x ^ y.y ^ y.z ^ y.w;
        uint4 z = c[i]; acc ^= z.x ^ z.y ^ z.z ^ z.w;
    }
    sink[blockIdx.x * 256 + threadIdx.x] = acc;
}

// ---------------------------------------------------------------------------
// Kernel 1: depthwise dilated 3x3 (dil=2, SAME) conv of key_in AND value
// (fp32 in), restaged head-major bf16: ws[(b*8+h)*1024 + s][d].
// K rows pre-scaled by SCALE_L2E (log2 domain for the attn exp2).
// One thread = 4 channels x 2 y-pixels (y0, y0+2); 24 float4 loads up-front.
// BYTE-IDENTICAL to R9.
// ---------------------------------------------------------------------------
__global__ __launch_bounds__(256) void dw_conv_kernel(
    const float* __restrict__ key_in, const float* __restrict__ value,
    const float* __restrict__ ck, const float* __restrict__ cb,
    u16* __restrict__ Kws, u16* __restrict__ Vws)
{
    int idx = blockIdx.x * 256 + threadIdx.x;  // (b, ypair, x, c4)
    int c4 = idx & 63;                         // 4-channel group
    int x  = (idx >> 6) & 31;
    int py = (idx >> 11) & 15;
    int b  = idx >> 15;
    int y0 = (py >> 1) * 4 + (py & 1);         // outputs y0 and y0+2

    const float4* K4 = (const float4*)key_in;  // [(b*32+y)*32+x]*64 + c4
    const float4* V4 = (const float4*)value;
    const float4 z4 = make_float4(0.f, 0.f, 0.f, 0.f);

    // ---- all taps up-front: 4 rows (y0-2,y0,y0+2,y0+4) x 3 cols, K and V ----
    float4 kk[4][3], vv[4][3];
    #pragma unroll
    for (int r = 0; r < 4; r++) {
        int yy = y0 - 2 + 2 * r;
        bool yok = (yy >= 0) && (yy < HH);
        #pragma unroll
        for (int ci = 0; ci < 3; ci++) {
            int xx = x - 2 + 2 * ci;
            bool ok = yok && (xx >= 0) && (xx < WW);
            size_t ii = ((((size_t)b * HH + yy) * WW) + xx) * 64 + c4;
            kk[r][ci] = ok ? K4[ii] : z4;
            vv[r][ci] = ok ? V4[ii] : z4;
        }
    }

    // ---- weights + bias (L1-resident after first wave) ----
    float4 w9[9];
    #pragma unroll
    for (int t = 0; t < 9; t++) w9[t] = *(const float4*)(ck + t * CC + 4 * c4);
    float4 bias4 = *(const float4*)(cb + 4 * c4);

    float4 kaA = bias4, vaA = bias4;           // output at y0
    float4 kaB = bias4, vaB = bias4;           // output at y0+2
    #pragma unroll
    for (int kh = 0; kh < 3; kh++) {
        #pragma unroll
        for (int kw = 0; kw < 3; kw++) {
            float4 w = w9[kh * 3 + kw];
            float4 a, v;
            a = kk[kh][kw];     kaA.x += w.x*a.x; kaA.y += w.y*a.y; kaA.z += w.z*a.z; kaA.w += w.w*a.w;
            v = vv[kh][kw];     vaA.x += w.x*v.x; vaA.y += w.y*v.y; vaA.z += w.z*v.z; vaA.w += w.w*v.w;
            a = kk[kh + 1][kw]; kaB.x += w.x*a.x; kaB.y += w.y*a.y; kaB.z += w.z*a.z; kaB.w += w.w*a.w;
            v = vv[kh + 1][kw]; vaB.x += w.x*v.x; vaB.y += w.y*v.y; vaB.z += w.z*v.z; vaB.w += w.w*v.w;
        }
    }

    int h = c4 >> 3;                 // (4*c4)>>5
    int d = (c4 & 7) * 4;            // (4*c4)&31
    size_t base = ((size_t)(b * HEADS + h)) * S_ * HD + d;
    size_t oA = base + (size_t)(y0 * WW + x) * HD;
    size_t oB = base + (size_t)((y0 + 2) * WW + x) * HD;
    *(uint2*)&Kws[oA] = make_uint2(pack2bf(kaA.x * SCALE_L2E, kaA.y * SCALE_L2E),
                                   pack2bf(kaA.z * SCALE_L2E, kaA.w * SCALE_L2E));
    *(uint2*)&Vws[oA] = make_uint2(pack2bf(vaA.x, vaA.y), pack2bf(vaA.z, vaA.w));
    *(uint2*)&Kws[oB] = make_uint2(pack2bf(kaB.x * SCALE_L2E, kaB.y * SCALE_L2E),
                                   pack2bf(kaB.z * SCALE_L2E, kaB.w * SCALE_L2E));
    *(uint2*)&Vws[oB] = make_uint2(pack2bf(vaB.x, vaB.y), pack2bf(vaB.z, vaB.w));
}

// ---------------------------------------------------------------------------
// Kernel 2: MFMA flash attention, double-buffered (byte-identical to R7/R8/R9).
//   S^T = K * Q^T ; P = exp2(S^T) (fixed max) ; O^T = V^T * P^T ;
//   Dsum = ones * P^T  (denominator; every reg = sum over keys for q=lane&15)
// V^T staged with per-32-chunk column permutation pos(Q,t',r) <- key(t',Q,r)
// so B-operand k-slot 8Q+j pairs with C-layout reg (t'=j>=4, r=j&3) of quad Q.
// ---------------------------------------------------------------------------
__global__ __launch_bounds__(256, 4) void attn_kernel(
    const float* __restrict__ query,
    const u16* __restrict__ Kws, const u16* __restrict__ Vws,
    float* __restrict__ out)
{
    __shared__ __align__(16) u16 Klds[2][KT][40];       // 2 x 10.0 KB
    __shared__ __align__(16) u16 Vtlds[2][HD][KT + 8];  // 2 x 8.5 KB

    const int tid  = threadIdx.x;
    const int lane = tid & 63;
    const int wv   = tid >> 6;
    const int q15  = lane & 15;
    const int quad = lane >> 4;

    const int blk = blockIdx.x;        // 1024 = 128 bh * 8 qtiles
    const int bh  = blk >> 3;
    const int qt  = blk & 7;
    const int b = bh >> 3, h = bh & 7;
    const int q0w = qt * 128 + wv * 32;  // wave's first query

    // ---- Q fragments: 2 x (16 rows x 32 d), fp32 global -> bf16 regs ----
    short8 qf[2];
    #pragma unroll
    for (int f = 0; f < 2; f++) {
        const float* qp = query + ((size_t)(b * S_ + q0w + f * 16 + q15)) * CC
                          + h * HD + quad * 8;
        float4 a = *(const float4*)(qp);
        float4 c = *(const float4*)(qp + 4);
        short8 v;
        v[0] = (short)f2bf(a.x); v[1] = (short)f2bf(a.y);
        v[2] = (short)f2bf(a.z); v[3] = (short)f2bf(a.w);
        v[4] = (short)f2bf(c.x); v[5] = (short)f2bf(c.y);
        v[6] = (short)f2bf(c.z); v[7] = (short)f2bf(c.w);
        qf[f] = v;
    }

    short8 ones;                       // bf16 1.0 = 0x3F80
    #pragma unroll
    for (int j = 0; j < 8; j++) ones[j] = (short)0x3F80;

    const u16* Kg = Kws + (size_t)bh * S_ * HD;
    const u16* Vg = Vws + (size_t)bh * S_ * HD;

    // ---- staging geometry (fixed per thread) ----
    const int krow = tid >> 1, khalf = tid & 1;
    const int vg  = tid >> 3, vs4 = tid & 7;
    const int vc = vg >> 3, vw = vg & 7;
    const int vt2 = (vw >> 2) & 1, vqd = vw & 3;
    const int vpg = (vc << 5) | (vqd << 3) | (vt2 << 2);   // permuted col base

    uint4 kra, krb;                    // K stage regs (32 B/thread)
    uint2 vr0, vr1, vr2, vr3;          // V stage regs (32 B/thread)

    auto issue_loads = [&](int kt0) {
        const uint4* ksrc = (const uint4*)(Kg + (size_t)(kt0 + krow) * HD + khalf * 16);
        kra = ksrc[0]; krb = ksrc[1];
        const uint2* vsrc = (const uint2*)(Vg + (size_t)(kt0 + 4 * vg) * HD + 4 * vs4);
        vr0 = vsrc[0]; vr1 = vsrc[8]; vr2 = vsrc[16]; vr3 = vsrc[24];
    };
    auto write_lds = [&](int p) {
        uint4* kdst = (uint4*)&Klds[p][krow][khalf * 16];
        kdst[0] = kra; kdst[1] = krb;
        u32 a, bb;
        a  = __builtin_amdgcn_perm(vr1.x, vr0.x, 0x05040100u);
        bb = __builtin_amdgcn_perm(vr3.x, vr2.x, 0x05040100u);
        *(uint2*)&Vtlds[p][4 * vs4 + 0][vpg] = make_uint2(a, bb);
        a  = __builtin_amdgcn_perm(vr1.x, vr0.x, 0x07060302u);
        bb = __builtin_amdgcn_perm(vr3.x, vr2.x, 0x07060302u);
        *(uint2*)&Vtlds[p][4 * vs4 + 1][vpg] = make_uint2(a, bb);
        a  = __builtin_amdgcn_perm(vr1.y, vr0.y, 0x05040100u);
        bb = __builtin_amdgcn_perm(vr3.y, vr2.y, 0x05040100u);
        *(uint2*)&Vtlds[p][4 * vs4 + 2][vpg] = make_uint2(a, bb);
        a  = __builtin_amdgcn_perm(vr1.y, vr0.y, 0x07060302u);
        bb = __builtin_amdgcn_perm(vr3.y, vr2.y, 0x07060302u);
        *(uint2*)&Vtlds[p][4 * vs4 + 3][vpg] = make_uint2(a, bb);
    };

    f32x4 Ot[2][2];                    // [frag][dhalf], C-layout (rows = d)
    f32x4 Dsum[2];                     // denominator accumulator
    #pragma unroll
    for (int f = 0; f < 2; f++) {
        Ot[f][0] = (f32x4)0.f; Ot[f][1] = (f32x4)0.f; Dsum[f] = (f32x4)0.f;
    }

    issue_loads(0);
    write_lds(0);                      // prologue: buffer 0

    for (int it = 0; it < NITER; it++) {
        const int p = it & 1;
        if (it + 1 < NITER) issue_loads((it + 1) * KT);   // in flight across barrier+compute
        __syncthreads();               // buf p writes visible; prev readers of buf 1-p done

        // ---- chunk-fused: QK -> exp2 -> pack -> PV per 32 keys ----
        #pragma unroll
        for (int c = 0; c < 4; c++) {
            short8 kf0 = *(const short8*)&Klds[p][c * 32 + q15][quad * 8];
            short8 kf1 = *(const short8*)&Klds[p][c * 32 + 16 + q15][quad * 8];
            short8 vf0 = *(const short8*)&Vtlds[p][q15][c * 32 + quad * 8];
            short8 vf1 = *(const short8*)&Vtlds[p][16 + q15][c * 32 + quad * 8];
            #pragma unroll
            for (int f = 0; f < 2; f++) {
                f32x4 s0 = __builtin_amdgcn_mfma_f32_16x16x32_bf16(kf0, qf[f], (f32x4)0.f, 0, 0, 0);
                f32x4 s1 = __builtin_amdgcn_mfma_f32_16x16x32_bf16(kf1, qf[f], (f32x4)0.f, 0, 0, 0);
                #pragma unroll
                for (int r = 0; r < 4; r++) {
                    s0[r] = __builtin_amdgcn_exp2f(s0[r]);
                    s1[r] = __builtin_amdgcn_exp2f(s1[r]);
                }
                union { u32 u[4]; short8 s8; } pk;   // bf16-truncate pack
                pk.u[0] = __builtin_amdgcn_perm(__float_as_uint(s0[1]),
                                                __float_as_uint(s0[0]), 0x07060302u);
                pk.u[1] = __builtin_amdgcn_perm(__float_as_uint(s0[3]),
                                                __float_as_uint(s0[2]), 0x07060302u);
                pk.u[2] = __builtin_amdgcn_perm(__float_as_uint(s1[1]),
                                                __float_as_uint(s1[0]), 0x07060302u);
                pk.u[3] = __builtin_amdgcn_perm(__float_as_uint(s1[3]),
                                                __float_as_uint(s1[2]), 0x07060302u);
                Ot[f][0] = __builtin_amdgcn_mfma_f32_16x16x32_bf16(vf0, pk.s8, Ot[f][0], 0, 0, 0);
                Ot[f][1] = __builtin_amdgcn_mfma_f32_16x16x32_bf16(vf1, pk.s8, Ot[f][1], 0, 0, 0);
                Dsum[f]  = __builtin_amdgcn_mfma_f32_16x16x32_bf16(ones, pk.s8, Dsum[f], 0, 0, 0);
            }
        }
        if (it + 1 < NITER) write_lds((it + 1) & 1);      // idle buffer; next barrier publishes
    }

    // ---- epilogue: O^T[d][q] / Dsum[q] -> out[b][q][h*32+d] ----
    #pragma unroll
    for (int f = 0; f < 2; f++) {
        float inv = 1.0f / Dsum[f][0];
        int qg = q0w + f * 16 + q15;
        float* op = out + ((size_t)(b * S_ + qg)) * CC + h * HD;
        #pragma unroll
        for (int h2 = 0; h2 < 2; h2++)
            #pragma unroll
            for (int r = 0; r < 4; r++)
                op[h2 * 16 + quad * 4 + r] = Ot[f][h2][r] * inv;
    }
}

// ---------------------------------------------------------------------------
extern "C" void kernel_launch(void* const* d_in, const int* in_sizes, int n_in,
                              void* d_out, int out_size, void* d_ws, size_t ws_size,
                              hipStream_t stream)
{
    const float* query  = (const float*)d_in[0];
    const float* key_in = (const float*)d_in[1];
    const float* value  = (const float*)d_in[2];
    const float* ck     = (const float*)d_in[3];
    const float* cb     = (const float*)d_in[4];
    float* out = (float*)d_out;

    u16* Kws = (u16*)d_ws;                               // 8.39 MB
    u16* Vws = Kws + (size_t)B_ * HEADS * S_ * HD;       // 8.39 MB
    u32* sink = (u32*)((char*)d_ws + (32u << 20));       // 1 MB sink at +32MB

    // L3 pre-warm: stream all three input tensors (50MB) sequentially.
    touch_kernel<<<1024, 256, 0, stream>>>(
        (const uint4*)key_in, (const uint4*)value, (const uint4*)query, sink);

    // 4 channels x 2 y-pixels per thread: grid = 16*16*32*64 / 256 = 2048 blocks.
    dw_conv_kernel<<<(B_ * 16 * WW * (CC / 4)) / 256, 256, 0, stream>>>(
        key_in, value, ck, cb, Kws, Vws);

    // 128 queries per block (4 waves x 32): grid = 131072/128 = 1024 blocks.
    attn_kernel<<<(B_ * HEADS * S_) / 128, 256, 0, stream>>>(
        query, Kws, Vws, out);
}

// Round 11
// 135.513 us; speedup vs baseline: 1.1931x; 1.1931x over previous
//
#include <hip/hip_runtime.h>

// DilatedSpatialAttention — round 11: touch reverted; conv = max-TLP split-K/V.
// DTYPES (established rounds 0-2): inputs fp32, output fp32.
// R10 falsified the cold-L3 theory: pre-warming inputs changed nothing (conv
// 43us, FETCH 30.8MB before and after). Conv record R7-R10: no throughput
// resource explains 43us; only more/smaller threads ever helped (R8, -10us);
// occupancy ~23% in all variants => concurrency-starved latency gather.
// R11: (1) drop touch (+9us free); (2) conv threads split by tensor (K or V):
// 2.1M threads / 8192 blocks, 19 loads/thread, half the dependency chain,
// same FMA order => conv bit-identical. Attn byte-identical to R7/R8/R9.
// absmax must stay exactly 1.220703e-4.
#define B_    16
#define HH    32
#define WW    32
#define CC    256
#define HEADS 8
#define HD    32
#define S_    1024
#define KT    128                 // keys per LDS tile
#define NITER (S_ / KT)           // 8
#define SCALE_L2E 0.25503486f     // 32^-0.5 * log2(e)  (pre-folded into Kws)

typedef unsigned short u16;
typedef unsigned int   u32;
typedef __attribute__((ext_vector_type(8))) short short8;  // 8 bf16 (A/B frag)
typedef __attribute__((ext_vector_type(4))) float f32x4;   // C/D frag

__device__ __forceinline__ u16 f2bf(float f) {             // RNE
    u32 x = __float_as_uint(f);
    return (u16)((x + 0x7fffu + ((x >> 16) & 1u)) >> 16);
}
__device__ __forceinline__ u32 pack2bf(float lo, float hi) {
    return (u32)f2bf(lo) | ((u32)f2bf(hi) << 16);
}

// ---------------------------------------------------------------------------
// Kernel 1: depthwise dilated 3x3 (dil=2, SAME) conv. One thread = 4 channels
// of ONE pixel of ONE tensor (K or V): 2.1M threads, 19 loads each.
// Output head-major bf16: ws[(b*8+h)*1024 + s][d]; K pre-scaled by SCALE_L2E.
// ---------------------------------------------------------------------------
__global__ __launch_bounds__(256) void dw_conv_kernel(
    const float* __restrict__ key_in, const float* __restrict__ value,
    const float* __restrict__ ck, const float* __restrict__ cb,
    u16* __restrict__ Kws, u16* __restrict__ Vws)
{
    int idx = blockIdx.x * 256 + threadIdx.x;  // (t, b, y, x, c4)
    int c4 = idx & 63;                         // 4-channel group
    int x  = (idx >> 6) & 31;
    int y  = (idx >> 11) & 31;
    int b  = (idx >> 16) & 15;
    int t  = idx >> 20;                        // 0 = key, 1 = value (wave-uniform)
    const float* __restrict__ src = t ? value : key_in;

    float4 acc = *(const float4*)(cb + 4 * c4);    // bias first (order-preserving)
    #pragma unroll
    for (int kh = 0; kh < 3; kh++) {
        int yy = y + kh * 2 - 2;
        if (yy < 0 || yy >= HH) continue;
        #pragma unroll
        for (int kw = 0; kw < 3; kw++) {
            int xx = x + kw * 2 - 2;
            if (xx < 0 || xx >= WW) continue;
            float4 w = *(const float4*)(ck + (kh * 3 + kw) * CC + 4 * c4);
            size_t ii = ((((size_t)b * HH + yy) * WW) + xx) * CC + 4 * c4;
            float4 v = *(const float4*)(src + ii);
            acc.x += w.x * v.x; acc.y += w.y * v.y;
            acc.z += w.z * v.z; acc.w += w.w * v.w;
        }
    }

    int h = c4 >> 3;                 // (4*c4)>>5
    int d = (c4 & 7) * 4;            // (4*c4)&31
    int s = y * WW + x;
    size_t o = (((size_t)(b * HEADS + h)) * S_ + s) * HD + d;
    if (t == 0) {
        *(uint2*)&Kws[o] = make_uint2(pack2bf(acc.x * SCALE_L2E, acc.y * SCALE_L2E),
                                      pack2bf(acc.z * SCALE_L2E, acc.w * SCALE_L2E));
    } else {
        *(uint2*)&Vws[o] = make_uint2(pack2bf(acc.x, acc.y), pack2bf(acc.z, acc.w));
    }
}

// ---------------------------------------------------------------------------
// Kernel 2: MFMA flash attention, double-buffered (byte-identical to R7-R10).
//   S^T = K * Q^T ; P = exp2(S^T) (fixed max) ; O^T = V^T * P^T ;
//   Dsum = ones * P^T  (denominator; every reg = sum over keys for q=lane&15)
// V^T staged with per-32-chunk column permutation pos(Q,t',r) <- key(t',Q,r)
// so B-operand k-slot 8Q+j pairs with C-layout reg (t'=j>=4, r=j&3) of quad Q.
// ---------------------------------------------------------------------------
__global__ __launch_bounds__(256, 4) void attn_kernel(
    const float* __restrict__ query,
    const u16* __restrict__ Kws, const u16* __restrict__ Vws,
    float* __restrict__ out)
{
    __shared__ __align__(16) u16 Klds[2][KT][40];       // 2 x 10.0 KB
    __shared__ __align__(16) u16 Vtlds[2][HD][KT + 8];  // 2 x 8.5 KB

    const int tid  = threadIdx.x;
    const int lane = tid & 63;
    const int wv   = tid >> 6;
    const int q15  = lane & 15;
    const int quad = lane >> 4;

    const int blk = blockIdx.x;        // 1024 = 128 bh * 8 qtiles
    const int bh  = blk >> 3;
    const int qt  = blk & 7;
    const int b = bh >> 3, h = bh & 7;
    const int q0w = qt * 128 + wv * 32;  // wave's first query

    // ---- Q fragments: 2 x (16 rows x 32 d), fp32 global -> bf16 regs ----
    short8 qf[2];
    #pragma unroll
    for (int f = 0; f < 2; f++) {
        const float* qp = query + ((size_t)(b * S_ + q0w + f * 16 + q15)) * CC
                          + h * HD + quad * 8;
        float4 a = *(const float4*)(qp);
        float4 c = *(const float4*)(qp + 4);
        short8 v;
        v[0] = (short)f2bf(a.x); v[1] = (short)f2bf(a.y);
        v[2] = (short)f2bf(a.z); v[3] = (short)f2bf(a.w);
        v[4] = (short)f2bf(c.x); v[5] = (short)f2bf(c.y);
        v[6] = (short)f2bf(c.z); v[7] = (short)f2bf(c.w);
        qf[f] = v;
    }

    short8 ones;                       // bf16 1.0 = 0x3F80
    #pragma unroll
    for (int j = 0; j < 8; j++) ones[j] = (short)0x3F80;

    const u16* Kg = Kws + (size_t)bh * S_ * HD;
    const u16* Vg = Vws + (size_t)bh * S_ * HD;

    // ---- staging geometry (fixed per thread) ----
    const int krow = tid >> 1, khalf = tid & 1;
    const int vg  = tid >> 3, vs4 = tid & 7;
    const int vc = vg >> 3, vw = vg & 7;
    const int vt2 = (vw >> 2) & 1, vqd = vw & 3;
    const int vpg = (vc << 5) | (vqd << 3) | (vt2 << 2);   // permuted col base

    uint4 kra, krb;                    // K stage regs (32 B/thread)
    uint2 vr0, vr1, vr2, vr3;          // V stage regs (32 B/thread)

    auto issue_loads = [&](int kt0) {
        const uint4* ksrc = (const uint4*)(Kg + (size_t)(kt0 + krow) * HD + khalf * 16);
        kra = ksrc[0]; krb = ksrc[1];
        const uint2* vsrc = (const uint2*)(Vg + (size_t)(kt0 + 4 * vg) * HD + 4 * vs4);
        vr0 = vsrc[0]; vr1 = vsrc[8]; vr2 = vsrc[16]; vr3 = vsrc[24];
    };
    auto write_lds = [&](int p) {
        uint4* kdst = (uint4*)&Klds[p][krow][khalf * 16];
        kdst[0] = kra; kdst[1] = krb;
        u32 a, bb;
        a  = __builtin_amdgcn_perm(vr1.x, vr0.x, 0x05040100u);
        bb = __builtin_amdgcn_perm(vr3.x, vr2.x, 0x05040100u);
        *(uint2*)&Vtlds[p][4 * vs4 + 0][vpg] = make_uint2(a, bb);
        a  = __builtin_amdgcn_perm(vr1.x, vr0.x, 0x07060302u);
        bb = __builtin_amdgcn_perm(vr3.x, vr2.x, 0x07060302u);
        *(uint2*)&Vtlds[p][4 * vs4 + 1][vpg] = make_uint2(a, bb);
        a  = __builtin_amdgcn_perm(vr1.y, vr0.y, 0x05040100u);
        bb = __builtin_amdgcn_perm(vr3.y, vr2.y, 0x05040100u);
        *(uint2*)&Vtlds[p][4 * vs4 + 2][vpg] = make_uint2(a, bb);
        a  = __builtin_amdgcn_perm(vr1.y, vr0.y, 0x07060302u);
        bb = __builtin_amdgcn_perm(vr3.y, vr2.y, 0x07060302u);
        *(uint2*)&Vtlds[p][4 * vs4 + 3][vpg] = make_uint2(a, bb);
    };

    f32x4 Ot[2][2];                    // [frag][dhalf], C-layout (rows = d)
    f32x4 Dsum[2];                     // denominator accumulator
    #pragma unroll
    for (int f = 0; f < 2; f++) {
        Ot[f][0] = (f32x4)0.f; Ot[f][1] = (f32x4)0.f; Dsum[f] = (f32x4)0.f;
    }

    issue_loads(0);
    write_lds(0);                      // prologue: buffer 0

    for (int it = 0; it < NITER; it++) {
        const int p = it & 1;
        if (it + 1 < NITER) issue_loads((it + 1) * KT);   // in flight across barrier+compute
        __syncthreads();               // buf p writes visible; prev readers of buf 1-p done

        // ---- chunk-fused: QK -> exp2 -> pack -> PV per 32 keys ----
        #pragma unroll
        for (int c = 0; c < 4; c++) {
            short8 kf0 = *(const short8*)&Klds[p][c * 32 + q15][quad * 8];
            short8 kf1 = *(const short8*)&Klds[p][c * 32 + 16 + q15][quad * 8];
            short8 vf0 = *(const short8*)&Vtlds[p][q15][c * 32 + quad * 8];
            short8 vf1 = *(const short8*)&Vtlds[p][16 + q15][c * 32 + quad * 8];
            #pragma unroll
            for (int f = 0; f < 2; f++) {
                f32x4 s0 = __builtin_amdgcn_mfma_f32_16x16x32_bf16(kf0, qf[f], (f32x4)0.f, 0, 0, 0);
                f32x4 s1 = __builtin_amdgcn_mfma_f32_16x16x32_bf16(kf1, qf[f], (f32x4)0.f, 0, 0, 0);
                #pragma unroll
                for (int r = 0; r < 4; r++) {
                    s0[r] = __builtin_amdgcn_exp2f(s0[r]);
                    s1[r] = __builtin_amdgcn_exp2f(s1[r]);
                }
                union { u32 u[4]; short8 s8; } pk;   // bf16-truncate pack
                pk.u[0] = __builtin_amdgcn_perm(__float_as_uint(s0[1]),
                                                __float_as_uint(s0[0]), 0x07060302u);
                pk.u[1] = __builtin_amdgcn_perm(__float_as_uint(s0[3]),
                                                __float_as_uint(s0[2]), 0x07060302u);
                pk.u[2] = __builtin_amdgcn_perm(__float_as_uint(s1[1]),
                                                __float_as_uint(s1[0]), 0x07060302u);
                pk.u[3] = __builtin_amdgcn_perm(__float_as_uint(s1[3]),
                                                __float_as_uint(s1[2]), 0x07060302u);
                Ot[f][0] = __builtin_amdgcn_mfma_f32_16x16x32_bf16(vf0, pk.s8, Ot[f][0], 0, 0, 0);
                Ot[f][1] = __builtin_amdgcn_mfma_f32_16x16x32_bf16(vf1, pk.s8, Ot[f][1], 0, 0, 0);
                Dsum[f]  = __builtin_amdgcn_mfma_f32_16x16x32_bf16(ones, pk.s8, Dsum[f], 0, 0, 0);
            }
        }
        if (it + 1 < NITER) write_lds((it + 1) & 1);      // idle buffer; next barrier publishes
    }

    // ---- epilogue: O^T[d][q] / Dsum[q] -> out[b][q][h*32+d] ----
    #pragma unroll
    for (int f = 0; f < 2; f++) {
        float inv = 1.0f / Dsum[f][0];
        int qg = q0w + f * 16 + q15;
        float* op = out + ((size_t)(b * S_ + qg)) * CC + h * HD;
        #pragma unroll
        for (int h2 = 0; h2 < 2; h2++)
            #pragma unroll
            for (int r = 0; r < 4; r++)
                op[h2 * 16 + quad * 4 + r] = Ot[f][h2][r] * inv;
    }
}

// ---------------------------------------------------------------------------
extern "C" void kernel_launch(void* const* d_in, const int* in_sizes, int n_in,
                              void* d_out, int out_size, void* d_ws, size_t ws_size,
                              hipStream_t stream)
{
    const float* query  = (const float*)d_in[0];
    const float* key_in = (const float*)d_in[1];
    const float* value  = (const float*)d_in[2];
    const float* ck     = (const float*)d_in[3];
    const float* cb     = (const float*)d_in[4];
    float* out = (float*)d_out;

    u16* Kws = (u16*)d_ws;                               // 8.39 MB
    u16* Vws = Kws + (size_t)B_ * HEADS * S_ * HD;       // 8.39 MB

    // One tensor x 4 channels x 1 pixel per thread: grid = 2*16*32*32*64/256.
    dw_conv_kernel<<<(2 * B_ * HH * WW * (CC / 4)) / 256, 256, 0, stream>>>(
        key_in, value, ck, cb, Kws, Vws);

    // 128 queries per block (4 waves x 32): grid = 131072/128 = 1024 blocks.
    attn_kernel<<<(B_ * HEADS * S_) / 128, 256, 0, stream>>>(
        query, Kws, Vws, out);
}

// Round 12
// 134.255 us; speedup vs baseline: 1.2043x; 1.0094x over previous
//
#include <hip/hip_runtime.h>

// DilatedSpatialAttention — round 12: attn reads K-fragments direct from L2.
// DTYPES (established rounds 0-2): inputs fp32, output fp32.
// Budget (R11): ~62us harness fill/restore overhead (untouchable), conv ~28us
// (TLP-saturated), attn ~37us of which ds_read ~10us is the largest pipe term.
// Kws layout [key][d] IS the A-frag layout, so kf loads go straight from
// global/L2 (16B/lane), issued BEFORE __syncthreads so L2 latency hides in
// the barrier wait. Deletes Klds + its ds_writes + staging loads; halves all
// LDS traffic. V keeps the LDS transpose (permuted layout not loadable).
// conv byte-identical to R11; math identical => absmax exactly 1.220703e-4.
#define B_    16
#define HH    32
#define WW    32
#define CC    256
#define HEADS 8
#define HD    32
#define S_    1024
#define KT    128                 // keys per tile
#define NITER (S_ / KT)           // 8
#define SCALE_L2E 0.25503486f     // 32^-0.5 * log2(e)  (pre-folded into Kws)

typedef unsigned short u16;
typedef unsigned int   u32;
typedef __attribute__((ext_vector_type(8))) short short8;  // 8 bf16 (A/B frag)
typedef __attribute__((ext_vector_type(4))) float f32x4;   // C/D frag

__device__ __forceinline__ u16 f2bf(float f) {             // RNE
    u32 x = __float_as_uint(f);
    return (u16)((x + 0x7fffu + ((x >> 16) & 1u)) >> 16);
}
__device__ __forceinline__ u32 pack2bf(float lo, float hi) {
    return (u32)f2bf(lo) | ((u32)f2bf(hi) << 16);
}

// ---------------------------------------------------------------------------
// Kernel 1: depthwise dilated 3x3 (dil=2, SAME) conv. One thread = 4 channels
// of ONE pixel of ONE tensor (K or V): 2.1M threads, 19 loads each.
// Output head-major bf16: ws[(b*8+h)*1024 + s][d]; K pre-scaled by SCALE_L2E.
// BYTE-IDENTICAL to R11.
// ---------------------------------------------------------------------------
__global__ __launch_bounds__(256) void dw_conv_kernel(
    const float* __restrict__ key_in, const float* __restrict__ value,
    const float* __restrict__ ck, const float* __restrict__ cb,
    u16* __restrict__ Kws, u16* __restrict__ Vws)
{
    int idx = blockIdx.x * 256 + threadIdx.x;  // (t, b, y, x, c4)
    int c4 = idx & 63;                         // 4-channel group
    int x  = (idx >> 6) & 31;
    int y  = (idx >> 11) & 31;
    int b  = (idx >> 16) & 15;
    int t  = idx >> 20;                        // 0 = key, 1 = value (wave-uniform)
    const float* __restrict__ src = t ? value : key_in;

    float4 acc = *(const float4*)(cb + 4 * c4);    // bias first (order-preserving)
    #pragma unroll
    for (int kh = 0; kh < 3; kh++) {
        int yy = y + kh * 2 - 2;
        if (yy < 0 || yy >= HH) continue;
        #pragma unroll
        for (int kw = 0; kw < 3; kw++) {
            int xx = x + kw * 2 - 2;
            if (xx < 0 || xx >= WW) continue;
            float4 w = *(const float4*)(ck + (kh * 3 + kw) * CC + 4 * c4);
            size_t ii = ((((size_t)b * HH + yy) * WW) + xx) * CC + 4 * c4;
            float4 v = *(const float4*)(src + ii);
            acc.x += w.x * v.x; acc.y += w.y * v.y;
            acc.z += w.z * v.z; acc.w += w.w * v.w;
        }
    }

    int h = c4 >> 3;                 // (4*c4)>>5
    int d = (c4 & 7) * 4;            // (4*c4)&31
    int s = y * WW + x;
    size_t o = (((size_t)(b * HEADS + h)) * S_ + s) * HD + d;
    if (t == 0) {
        *(uint2*)&Kws[o] = make_uint2(pack2bf(acc.x * SCALE_L2E, acc.y * SCALE_L2E),
                                      pack2bf(acc.z * SCALE_L2E, acc.w * SCALE_L2E));
    } else {
        *(uint2*)&Vws[o] = make_uint2(pack2bf(acc.x, acc.y), pack2bf(acc.z, acc.w));
    }
}

// ---------------------------------------------------------------------------
// Kernel 2: MFMA flash attention. K-fragments loaded DIRECT from global
// (Kws[key][d] == A-frag layout), issued pre-barrier so L2 latency hides in
// the barrier wait. V^T double-buffered in LDS with the per-32-chunk column
// permutation pos(Q,t',r) <- key(t',Q,r) (B-slot 8Q+j pairs with C-layout
// reg (t'=j>=4, r=j&3) of quad Q). Fixed-max softmax in log2 domain;
// denominator via mfma(ones, pk, Dsum).
// ---------------------------------------------------------------------------
__global__ __launch_bounds__(256, 4) void attn_kernel(
    const float* __restrict__ query,
    const u16* __restrict__ Kws, const u16* __restrict__ Vws,
    float* __restrict__ out)
{
    __shared__ __align__(16) u16 Vtlds[2][HD][KT + 8];  // 2 x 8.5 KB (K LDS gone)

    const int tid  = threadIdx.x;
    const int lane = tid & 63;
    const int wv   = tid >> 6;
    const int q15  = lane & 15;
    const int quad = lane >> 4;

    const int blk = blockIdx.x;        // 1024 = 128 bh * 8 qtiles
    const int bh  = blk >> 3;
    const int qt  = blk & 7;
    const int b = bh >> 3, h = bh & 7;
    const int q0w = qt * 128 + wv * 32;  // wave's first query

    // ---- Q fragments: 2 x (16 rows x 32 d), fp32 global -> bf16 regs ----
    short8 qf[2];
    #pragma unroll
    for (int f = 0; f < 2; f++) {
        const float* qp = query + ((size_t)(b * S_ + q0w + f * 16 + q15)) * CC
                          + h * HD + quad * 8;
        float4 a = *(const float4*)(qp);
        float4 c = *(const float4*)(qp + 4);
        short8 v;
        v[0] = (short)f2bf(a.x); v[1] = (short)f2bf(a.y);
        v[2] = (short)f2bf(a.z); v[3] = (short)f2bf(a.w);
        v[4] = (short)f2bf(c.x); v[5] = (short)f2bf(c.y);
        v[6] = (short)f2bf(c.z); v[7] = (short)f2bf(c.w);
        qf[f] = v;
    }

    short8 ones;                       // bf16 1.0 = 0x3F80
    #pragma unroll
    for (int j = 0; j < 8; j++) ones[j] = (short)0x3F80;

    const u16* Kg = Kws + (size_t)bh * S_ * HD;
    const u16* Vg = Vws + (size_t)bh * S_ * HD;

    // ---- V staging geometry (fixed per thread) ----
    const int vg  = tid >> 3, vs4 = tid & 7;
    const int vc = vg >> 3, vw = vg & 7;
    const int vt2 = (vw >> 2) & 1, vqd = vw & 3;
    const int vpg = (vc << 5) | (vqd << 3) | (vt2 << 2);   // permuted col base

    uint2 vr0, vr1, vr2, vr3;          // V stage regs (32 B/thread)

    auto issue_v_loads = [&](int kt0) {
        const uint2* vsrc = (const uint2*)(Vg + (size_t)(kt0 + 4 * vg) * HD + 4 * vs4);
        vr0 = vsrc[0]; vr1 = vsrc[8]; vr2 = vsrc[16]; vr3 = vsrc[24];
    };
    auto write_lds = [&](int p) {
        u32 a, bb;
        a  = __builtin_amdgcn_perm(vr1.x, vr0.x, 0x05040100u);
        bb = __builtin_amdgcn_perm(vr3.x, vr2.x, 0x05040100u);
        *(uint2*)&Vtlds[p][4 * vs4 + 0][vpg] = make_uint2(a, bb);
        a  = __builtin_amdgcn_perm(vr1.x, vr0.x, 0x07060302u);
        bb = __builtin_amdgcn_perm(vr3.x, vr2.x, 0x07060302u);
        *(uint2*)&Vtlds[p][4 * vs4 + 1][vpg] = make_uint2(a, bb);
        a  = __builtin_amdgcn_perm(vr1.y, vr0.y, 0x05040100u);
        bb = __builtin_amdgcn_perm(vr3.y, vr2.y, 0x05040100u);
        *(uint2*)&Vtlds[p][4 * vs4 + 2][vpg] = make_uint2(a, bb);
        a  = __builtin_amdgcn_perm(vr1.y, vr0.y, 0x07060302u);
        bb = __builtin_amdgcn_perm(vr3.y, vr2.y, 0x07060302u);
        *(uint2*)&Vtlds[p][4 * vs4 + 3][vpg] = make_uint2(a, bb);
    };

    f32x4 Ot[2][2];                    // [frag][dhalf], C-layout (rows = d)
    f32x4 Dsum[2];                     // denominator accumulator
    #pragma unroll
    for (int f = 0; f < 2; f++) {
        Ot[f][0] = (f32x4)0.f; Ot[f][1] = (f32x4)0.f; Dsum[f] = (f32x4)0.f;
    }

    issue_v_loads(0);
    write_lds(0);                      // prologue: buffer 0

    for (int it = 0; it < NITER; it++) {
        const int p = it & 1;
        const int kt0 = it * KT;

        // ---- K fragments for THIS iter: direct global/L2, issued pre-barrier
        // (no LDS dependency -> latency hides in the barrier wait) ----
        short8 kfr0[4], kfr1[4];
        #pragma unroll
        for (int c = 0; c < 4; c++) {
            kfr0[c] = *(const short8*)(Kg + (size_t)(kt0 + c * 32 + q15) * HD + quad * 8);
            kfr1[c] = *(const short8*)(Kg + (size_t)(kt0 + c * 32 + 16 + q15) * HD + quad * 8);
        }
        if (it + 1 < NITER) issue_v_loads((it + 1) * KT);  // next V tile in flight
        __syncthreads();               // buf p writes visible; prev readers of 1-p done

        // ---- chunk-fused: QK -> exp2 -> pack -> PV per 32 keys ----
        #pragma unroll
        for (int c = 0; c < 4; c++) {
            short8 vf0 = *(const short8*)&Vtlds[p][q15][c * 32 + quad * 8];
            short8 vf1 = *(const short8*)&Vtlds[p][16 + q15][c * 32 + quad * 8];
            #pragma unroll
            for (int f = 0; f < 2; f++) {
                f32x4 s0 = __builtin_amdgcn_mfma_f32_16x16x32_bf16(kfr0[c], qf[f], (f32x4)0.f, 0, 0, 0);
                f32x4 s1 = __builtin_amdgcn_mfma_f32_16x16x32_bf16(kfr1[c], qf[f], (f32x4)0.f, 0, 0, 0);
                #pragma unroll
                for (int r = 0; r < 4; r++) {
                    s0[r] = __builtin_amdgcn_exp2f(s0[r]);
                    s1[r] = __builtin_amdgcn_exp2f(s1[r]);
                }
                union { u32 u[4]; short8 s8; } pk;   // bf16-truncate pack
                pk.u[0] = __builtin_amdgcn_perm(__float_as_uint(s0[1]),
                                                __float_as_uint(s0[0]), 0x07060302u);
                pk.u[1] = __builtin_amdgcn_perm(__float_as_uint(s0[3]),
                                                __float_as_uint(s0[2]), 0x07060302u);
                pk.u[2] = __builtin_amdgcn_perm(__float_as_uint(s1[1]),
                                                __float_as_uint(s1[0]), 0x07060302u);
                pk.u[3] = __builtin_amdgcn_perm(__float_as_uint(s1[3]),
                                                __float_as_uint(s1[2]), 0x07060302u);
                Ot[f][0] = __builtin_amdgcn_mfma_f32_16x16x32_bf16(vf0, pk.s8, Ot[f][0], 0, 0, 0);
                Ot[f][1] = __builtin_amdgcn_mfma_f32_16x16x32_bf16(vf1, pk.s8, Ot[f][1], 0, 0, 0);
                Dsum[f]  = __builtin_amdgcn_mfma_f32_16x16x32_bf16(ones, pk.s8, Dsum[f], 0, 0, 0);
            }
        }
        if (it + 1 < NITER) write_lds((it + 1) & 1);      // idle buffer; next barrier publishes
    }

    // ---- epilogue: O^T[d][q] / Dsum[q] -> out[b][q][h*32+d] ----
    #pragma unroll
    for (int f = 0; f < 2; f++) {
        float inv = 1.0f / Dsum[f][0];
        int qg = q0w + f * 16 + q15;
        float* op = out + ((size_t)(b * S_ + qg)) * CC + h * HD;
        #pragma unroll
        for (int h2 = 0; h2 < 2; h2++)
            #pragma unroll
            for (int r = 0; r < 4; r++)
                op[h2 * 16 + quad * 4 + r] = Ot[f][h2][r] * inv;
    }
}

// ---------------------------------------------------------------------------
extern "C" void kernel_launch(void* const* d_in, const int* in_sizes, int n_in,
                              void* d_out, int out_size, void* d_ws, size_t ws_size,
                              hipStream_t stream)
{
    const float* query  = (const float*)d_in[0];
    const float* key_in = (const float*)d_in[1];
    const float* value  = (const float*)d_in[2];
    const float* ck     = (const float*)d_in[3];
    const float* cb     = (const float*)d_in[4];
    float* out = (float*)d_out;

    u16* Kws = (u16*)d_ws;                               // 8.39 MB
    u16* Vws = Kws + (size_t)B_ * HEADS * S_ * HD;       // 8.39 MB

    // One tensor x 4 channels x 1 pixel per thread: grid = 2*16*32*32*64/256.
    dw_conv_kernel<<<(2 * B_ * HH * WW * (CC / 4)) / 256, 256, 0, stream>>>(
        key_in, value, ck, cb, Kws, Vws);

    // 128 queries per block (4 waves x 32): grid = 131072/128 = 1024 blocks.
    attn_kernel<<<(B_ * HEADS * S_) / 128, 256, 0, stream>>>(
        query, Kws, Vws, out);
}

// Round 13
// 133.753 us; speedup vs baseline: 1.2088x; 1.0038x over previous
//
#include <hip/hip_runtime.h>

// DilatedSpatialAttention — round 13: XCD-aware block swizzle for attn.
// DTYPES (established rounds 0-2): inputs fp32, output fp32.
// R12 (-1.3us for halving LDS) falsified LDS-throughput theory. Residual attn
// stall theory: blk = bh*8+qt maps the 8 same-bh qtile blocks to 8 DIFFERENT
// XCDs (blk%8 -> XCD), so each XCD L2 fetches its own copy of the bh's 128KB
// K/V slab from HBM (FETCH 73.8MB vs ~34 ideal, R5/R6) and R12's pre-barrier
// K loads miss to HBM (~900cyc) instead of XCD-L2 (~200cyc).
// Fix: decode bh = blk&127, qt = blk>>7 => same-bh blocks share blk%8 ->
// same XCD; 16 bh x 128KB = 2MB/XCD fits 4MB L2. Pure scheduling change;
// everything else byte-identical to R12. absmax must stay exactly 1.220703e-4.
#define B_    16
#define HH    32
#define WW    32
#define CC    256
#define HEADS 8
#define HD    32
#define S_    1024
#define KT    128                 // keys per tile
#define NITER (S_ / KT)           // 8
#define SCALE_L2E 0.25503486f     // 32^-0.5 * log2(e)  (pre-folded into Kws)

typedef unsigned short u16;
typedef unsigned int   u32;
typedef __attribute__((ext_vector_type(8))) short short8;  // 8 bf16 (A/B frag)
typedef __attribute__((ext_vector_type(4))) float f32x4;   // C/D frag

__device__ __forceinline__ u16 f2bf(float f) {             // RNE
    u32 x = __float_as_uint(f);
    return (u16)((x + 0x7fffu + ((x >> 16) & 1u)) >> 16);
}
__device__ __forceinline__ u32 pack2bf(float lo, float hi) {
    return (u32)f2bf(lo) | ((u32)f2bf(hi) << 16);
}

// ---------------------------------------------------------------------------
// Kernel 1: depthwise dilated 3x3 (dil=2, SAME) conv. One thread = 4 channels
// of ONE pixel of ONE tensor (K or V): 2.1M threads, 19 loads each.
// Output head-major bf16: ws[(b*8+h)*1024 + s][d]; K pre-scaled by SCALE_L2E.
// BYTE-IDENTICAL to R11/R12.
// ---------------------------------------------------------------------------
__global__ __launch_bounds__(256) void dw_conv_kernel(
    const float* __restrict__ key_in, const float* __restrict__ value,
    const float* __restrict__ ck, const float* __restrict__ cb,
    u16* __restrict__ Kws, u16* __restrict__ Vws)
{
    int idx = blockIdx.x * 256 + threadIdx.x;  // (t, b, y, x, c4)
    int c4 = idx & 63;                         // 4-channel group
    int x  = (idx >> 6) & 31;
    int y  = (idx >> 11) & 31;
    int b  = (idx >> 16) & 15;
    int t  = idx >> 20;                        // 0 = key, 1 = value (wave-uniform)
    const float* __restrict__ src = t ? value : key_in;

    float4 acc = *(const float4*)(cb + 4 * c4);    // bias first (order-preserving)
    #pragma unroll
    for (int kh = 0; kh < 3; kh++) {
        int yy = y + kh * 2 - 2;
        if (yy < 0 || yy >= HH) continue;
        #pragma unroll
        for (int kw = 0; kw < 3; kw++) {
            int xx = x + kw * 2 - 2;
            if (xx < 0 || xx >= WW) continue;
            float4 w = *(const float4*)(ck + (kh * 3 + kw) * CC + 4 * c4);
            size_t ii = ((((size_t)b * HH + yy) * WW) + xx) * CC + 4 * c4;
            float4 v = *(const float4*)(src + ii);
            acc.x += w.x * v.x; acc.y += w.y * v.y;
            acc.z += w.z * v.z; acc.w += w.w * v.w;
        }
    }

    int h = c4 >> 3;                 // (4*c4)>>5
    int d = (c4 & 7) * 4;            // (4*c4)&31
    int s = y * WW + x;
    size_t o = (((size_t)(b * HEADS + h)) * S_ + s) * HD + d;
    if (t == 0) {
        *(uint2*)&Kws[o] = make_uint2(pack2bf(acc.x * SCALE_L2E, acc.y * SCALE_L2E),
                                      pack2bf(acc.z * SCALE_L2E, acc.w * SCALE_L2E));
    } else {
        *(uint2*)&Vws[o] = make_uint2(pack2bf(acc.x, acc.y), pack2bf(acc.z, acc.w));
    }
}

// ---------------------------------------------------------------------------
// Kernel 2: MFMA flash attention. K-fragments direct from global/L2 (Kws
// [key][d] == A-frag layout), issued pre-barrier. V^T double-buffered in LDS
// with per-32-chunk column permutation pos(Q,t',r) <- key(t',Q,r). Fixed-max
// softmax in log2 domain; denominator via mfma(ones, pk, Dsum).
// R13: bh = blk&127 (qt = blk>>7) so same-bh blocks share an XCD.
// ---------------------------------------------------------------------------
__global__ __launch_bounds__(256, 4) void attn_kernel(
    const float* __restrict__ query,
    const u16* __restrict__ Kws, const u16* __restrict__ Vws,
    float* __restrict__ out)
{
    __shared__ __align__(16) u16 Vtlds[2][HD][KT + 8];  // 2 x 8.5 KB

    const int tid  = threadIdx.x;
    const int lane = tid & 63;
    const int wv   = tid >> 6;
    const int q15  = lane & 15;
    const int quad = lane >> 4;

    const int blk = blockIdx.x;        // 1024 blocks
    const int bh  = blk & 127;         // XCD swizzle: same bh -> same blk%8 -> same XCD
    const int qt  = blk >> 7;
    const int b = bh >> 3, h = bh & 7;
    const int q0w = qt * 128 + wv * 32;  // wave's first query

    // ---- Q fragments: 2 x (16 rows x 32 d), fp32 global -> bf16 regs ----
    short8 qf[2];
    #pragma unroll
    for (int f = 0; f < 2; f++) {
        const float* qp = query + ((size_t)(b * S_ + q0w + f * 16 + q15)) * CC
                          + h * HD + quad * 8;
        float4 a = *(const float4*)(qp);
        float4 c = *(const float4*)(qp + 4);
        short8 v;
        v[0] = (short)f2bf(a.x); v[1] = (short)f2bf(a.y);
        v[2] = (short)f2bf(a.z); v[3] = (short)f2bf(a.w);
        v[4] = (short)f2bf(c.x); v[5] = (short)f2bf(c.y);
        v[6] = (short)f2bf(c.z); v[7] = (short)f2bf(c.w);
        qf[f] = v;
    }

    short8 ones;                       // bf16 1.0 = 0x3F80
    #pragma unroll
    for (int j = 0; j < 8; j++) ones[j] = (short)0x3F80;

    const u16* Kg = Kws + (size_t)bh * S_ * HD;
    const u16* Vg = Vws + (size_t)bh * S_ * HD;

    // ---- V staging geometry (fixed per thread) ----
    const int vg  = tid >> 3, vs4 = tid & 7;
    const int vc = vg >> 3, vw = vg & 7;
    const int vt2 = (vw >> 2) & 1, vqd = vw & 3;
    const int vpg = (vc << 5) | (vqd << 3) | (vt2 << 2);   // permuted col base

    uint2 vr0, vr1, vr2, vr3;          // V stage regs (32 B/thread)

    auto issue_v_loads = [&](int kt0) {
        const uint2* vsrc = (const uint2*)(Vg + (size_t)(kt0 + 4 * vg) * HD + 4 * vs4);
        vr0 = vsrc[0]; vr1 = vsrc[8]; vr2 = vsrc[16]; vr3 = vsrc[24];
    };
    auto write_lds = [&](int p) {
        u32 a, bb;
        a  = __builtin_amdgcn_perm(vr1.x, vr0.x, 0x05040100u);
        bb = __builtin_amdgcn_perm(vr3.x, vr2.x, 0x05040100u);
        *(uint2*)&Vtlds[p][4 * vs4 + 0][vpg] = make_uint2(a, bb);
        a  = __builtin_amdgcn_perm(vr1.x, vr0.x, 0x07060302u);
        bb = __builtin_amdgcn_perm(vr3.x, vr2.x, 0x07060302u);
        *(uint2*)&Vtlds[p][4 * vs4 + 1][vpg] = make_uint2(a, bb);
        a  = __builtin_amdgcn_perm(vr1.y, vr0.y, 0x05040100u);
        bb = __builtin_amdgcn_perm(vr3.y, vr2.y, 0x05040100u);
        *(uint2*)&Vtlds[p][4 * vs4 + 2][vpg] = make_uint2(a, bb);
        a  = __builtin_amdgcn_perm(vr1.y, vr0.y, 0x07060302u);
        bb = __builtin_amdgcn_perm(vr3.y, vr2.y, 0x07060302u);
        *(uint2*)&Vtlds[p][4 * vs4 + 3][vpg] = make_uint2(a, bb);
    };

    f32x4 Ot[2][2];                    // [frag][dhalf], C-layout (rows = d)
    f32x4 Dsum[2];                     // denominator accumulator
    #pragma unroll
    for (int f = 0; f < 2; f++) {
        Ot[f][0] = (f32x4)0.f; Ot[f][1] = (f32x4)0.f; Dsum[f] = (f32x4)0.f;
    }

    issue_v_loads(0);
    write_lds(0);                      // prologue: buffer 0

    for (int it = 0; it < NITER; it++) {
        const int p = it & 1;
        const int kt0 = it * KT;

        // ---- K fragments for THIS iter: direct global/L2, issued pre-barrier
        // (no LDS dependency -> latency hides in the barrier wait) ----
        short8 kfr0[4], kfr1[4];
        #pragma unroll
        for (int c = 0; c < 4; c++) {
            kfr0[c] = *(const short8*)(Kg + (size_t)(kt0 + c * 32 + q15) * HD + quad * 8);
            kfr1[c] = *(const short8*)(Kg + (size_t)(kt0 + c * 32 + 16 + q15) * HD + quad * 8);
        }
        if (it + 1 < NITER) issue_v_loads((it + 1) * KT);  // next V tile in flight
        __syncthreads();               // buf p writes visible; prev readers of 1-p done

        // ---- chunk-fused: QK -> exp2 -> pack -> PV per 32 keys ----
        #pragma unroll
        for (int c = 0; c < 4; c++) {
            short8 vf0 = *(const short8*)&Vtlds[p][q15][c * 32 + quad * 8];
            short8 vf1 = *(const short8*)&Vtlds[p][16 + q15][c * 32 + quad * 8];
            #pragma unroll
            for (int f = 0; f < 2; f++) {
                f32x4 s0 = __builtin_amdgcn_mfma_f32_16x16x32_bf16(kfr0[c], qf[f], (f32x4)0.f, 0, 0, 0);
                f32x4 s1 = __builtin_amdgcn_mfma_f32_16x16x32_bf16(kfr1[c], qf[f], (f32x4)0.f, 0, 0, 0);
                #pragma unroll
                for (int r = 0; r < 4; r++) {
                    s0[r] = __builtin_amdgcn_exp2f(s0[r]);
                    s1[r] = __builtin_amdgcn_exp2f(s1[r]);
                }
                union { u32 u[4]; short8 s8; } pk;   // bf16-truncate pack
                pk.u[0] = __builtin_amdgcn_perm(__float_as_uint(s0[1]),
                                                __float_as_uint(s0[0]), 0x07060302u);
                pk.u[1] = __builtin_amdgcn_perm(__float_as_uint(s0[3]),
                                                __float_as_uint(s0[2]), 0x07060302u);
                pk.u[2] = __builtin_amdgcn_perm(__float_as_uint(s1[1]),
                                                __float_as_uint(s1[0]), 0x07060302u);
                pk.u[3] = __builtin_amdgcn_perm(__float_as_uint(s1[3]),
                                                __float_as_uint(s1[2]), 0x07060302u);
                Ot[f][0] = __builtin_amdgcn_mfma_f32_16x16x32_bf16(vf0, pk.s8, Ot[f][0], 0, 0, 0);
                Ot[f][1] = __builtin_amdgcn_mfma_f32_16x16x32_bf16(vf1, pk.s8, Ot[f][1], 0, 0, 0);
                Dsum[f]  = __builtin_amdgcn_mfma_f32_16x16x32_bf16(ones, pk.s8, Dsum[f], 0, 0, 0);
            }
        }
        if (it + 1 < NITER) write_lds((it + 1) & 1);      // idle buffer; next barrier publishes
    }

    // ---- epilogue: O^T[d][q] / Dsum[q] -> out[b][q][h*32+d] ----
    #pragma unroll
    for (int f = 0; f < 2; f++) {
        float inv = 1.0f / Dsum[f][0];
        int qg = q0w + f * 16 + q15;
        float* op = out + ((size_t)(b * S_ + qg)) * CC + h * HD;
        #pragma unroll
        for (int h2 = 0; h2 < 2; h2++)
            #pragma unroll
            for (int r = 0; r < 4; r++)
                op[h2 * 16 + quad * 4 + r] = Ot[f][h2][r] * inv;
    }
}

// ---------------------------------------------------------------------------
extern "C" void kernel_launch(void* const* d_in, const int* in_sizes, int n_in,
                              void* d_out, int out_size, void* d_ws, size_t ws_size,
                              hipStream_t stream)
{
    const float* query  = (const float*)d_in[0];
    const float* key_in = (const float*)d_in[1];
    const float* value  = (const float*)d_in[2];
    const float* ck     = (const float*)d_in[3];
    const float* cb     = (const float*)d_in[4];
    float* out = (float*)d_out;

    u16* Kws = (u16*)d_ws;                               // 8.39 MB
    u16* Vws = Kws + (size_t)B_ * HEADS * S_ * HD;       // 8.39 MB

    // One tensor x 4 channels x 1 pixel per thread: grid = 2*16*32*32*64/256.
    dw_conv_kernel<<<(2 * B_ * HH * WW * (CC / 4)) / 256, 256, 0, stream>>>(
        key_in, value, ck, cb, Kws, Vws);

    // 128 queries per block (4 waves x 32): grid = 131072/128 = 1024 blocks.
    // blk decode is XCD-swizzled inside the kernel (bh = blk&127).
    attn_kernel<<<(B_ * HEADS * S_) / 128, 256, 0, stream>>>(
        query, Kws, Vws, out);
}

// Round 14
// 128.439 us; speedup vs baseline: 1.2589x; 1.0414x over previous
//
#include <hip/hip_runtime.h>

// DilatedSpatialAttention — round 14: LDS-staged streaming conv.
// DTYPES (established rounds 0-2): inputs fp32, output fp32.
// Conv record: 4 thread-shape variants all ~34-44us, FETCH ~= compulsory,
// BW <= 1.9TB/s, VALU <= 24%, conflicts 0 => the scattered 9-tap dilated
// gather itself is the cost. R14 = Guideline 3: block stages a halo'd input
// tile (12 rows x 32 x x 32 ch, 48KB fp32) via fully-coalesced streaming
// loads; taps come from LDS (b128 stride-1 = conflict-free); halo'd y-tiles
// of same (b,ch) share blk%8 -> same XCD L2. Same per-output FMA order =>
// conv bit-identical => absmax must stay exactly 1.220703e-4.
// Attn BYTE-IDENTICAL to R13 (K direct from L2, V^T dbuf LDS, fixed-max
// log2-domain softmax, Dsum via mfma, XCD swizzle).
#define B_    16
#define HH    32
#define WW    32
#define CC    256
#define HEADS 8
#define HD    32
#define S_    1024
#define KT    128                 // keys per tile
#define NITER (S_ / KT)           // 8
#define SCALE_L2E 0.25503486f     // 32^-0.5 * log2(e)  (pre-folded into Kws)

typedef unsigned short u16;
typedef unsigned int   u32;
typedef __attribute__((ext_vector_type(8))) short short8;  // 8 bf16 (A/B frag)
typedef __attribute__((ext_vector_type(4))) float f32x4;   // C/D frag

__device__ __forceinline__ u16 f2bf(float f) {             // RNE
    u32 x = __float_as_uint(f);
    return (u16)((x + 0x7fffu + ((x >> 16) & 1u)) >> 16);
}
__device__ __forceinline__ u32 pack2bf(float lo, float hi) {
    return (u32)f2bf(lo) | ((u32)f2bf(hi) << 16);
}

// ---------------------------------------------------------------------------
// Kernel 1: depthwise dilated 3x3 (dil=2, SAME) conv, LDS-staged.
// Block = (tensor t, batch b, y-tile of 8 rows, head-group g of 32 ch).
// LDS tile: 12 rows (y0-2..y0+9) x 32 x x 8 float4 = 49152 B; 3 blocks/CU.
// Loads: 12 x 16B/thread, sequential+coalesced. Compute: 9 LDS taps/output,
// 8 outputs/thread (fixed c = tid&7 -> w9 loaded once).
// Output head-major bf16 ws[(b*8+h)*1024+s][d]; K pre-scaled by SCALE_L2E.
// ---------------------------------------------------------------------------
__global__ __launch_bounds__(256) void dw_conv_kernel(
    const float* __restrict__ key_in, const float* __restrict__ value,
    const float* __restrict__ ck, const float* __restrict__ cb,
    u16* __restrict__ Kws, u16* __restrict__ Vws)
{
    __shared__ float4 tile[3072];      // [r 0..11][x 0..31][c 0..7]

    const int tid = threadIdx.x;
    const int blk = blockIdx.x;        // 1024 = 2 t x 16 b x 4 yt x 8 g
    const int g  = blk & 7;            // 32-ch head group (head h = g)
    const int yt = (blk >> 3) & 3;     // y tile (8 rows)
    const int b  = (blk >> 5) & 15;
    const int t  = blk >> 9;           // 0 = key, 1 = value (block-uniform)
    const float4* __restrict__ src4 = (const float4*)(t ? value : key_in);
    const int y0 = yt * 8;

    // ---- stage halo'd tile: 12 slots/thread, streaming coalesced ----
    #pragma unroll
    for (int i = 0; i < 12; i++) {
        int slot = tid + i * 256;      // slot = (r*32 + x)*8 + c
        int r = slot >> 8, x = (slot >> 3) & 31, cc = slot & 7;
        int yy = y0 - 2 + r;
        float4 v = make_float4(0.f, 0.f, 0.f, 0.f);
        if (yy >= 0 && yy < HH)
            v = src4[(((size_t)b * HH + yy) * WW + x) * 64 + g * 8 + cc];
        tile[slot] = v;
    }

    // ---- per-thread fixed channel quad c = tid&7: weights + bias once ----
    const int c = tid & 7;
    float4 w9[9];
    #pragma unroll
    for (int j = 0; j < 9; j++)
        w9[j] = *(const float4*)(ck + j * CC + g * 32 + c * 4);
    const float4 bias = *(const float4*)(cb + g * 32 + c * 4);

    __syncthreads();

    // ---- compute 8 outputs/thread from LDS (bias-first, kh/kw ascending,
    //      OOB-skip: identical FMA order to R11 -> bit-identical conv) ----
    #pragma unroll
    for (int i = 0; i < 8; i++) {
        int o = tid + i * 256;         // o = (ry*32 + x)*8 + c
        int x = (o >> 3) & 31, ry = o >> 8;
        float4 acc = bias;
        #pragma unroll
        for (int kh = 0; kh < 3; kh++) {
            #pragma unroll
            for (int kw = 0; kw < 3; kw++) {
                int xx = x - 2 + 2 * kw;
                if (xx < 0 || xx >= WW) continue;   // y-OOB rows are zero in LDS
                float4 v = tile[((ry + 2 * kh) * 32 + xx) * 8 + c];
                float4 w = w9[kh * 3 + kw];
                acc.x += w.x * v.x; acc.y += w.y * v.y;
                acc.z += w.z * v.z; acc.w += w.w * v.w;
            }
        }
        int spix = (y0 + ry) * WW + x;
        size_t off = (((size_t)(b * HEADS + g)) * S_ + spix) * HD + c * 4;
        if (t == 0)
            *(uint2*)&Kws[off] = make_uint2(pack2bf(acc.x * SCALE_L2E, acc.y * SCALE_L2E),
                                            pack2bf(acc.z * SCALE_L2E, acc.w * SCALE_L2E));
        else
            *(uint2*)&Vws[off] = make_uint2(pack2bf(acc.x, acc.y), pack2bf(acc.z, acc.w));
    }
}

// ---------------------------------------------------------------------------
// Kernel 2: MFMA flash attention (BYTE-IDENTICAL to R13). K-fragments direct
// from global/L2 (Kws[key][d] == A-frag layout), issued pre-barrier. V^T
// double-buffered in LDS with per-32-chunk column permutation
// pos(Q,t',r) <- key(t',Q,r). Fixed-max softmax in log2 domain; denominator
// via mfma(ones, pk, Dsum). bh = blk&127 XCD swizzle.
// ---------------------------------------------------------------------------
__global__ __launch_bounds__(256, 4) void attn_kernel(
    const float* __restrict__ query,
    const u16* __restrict__ Kws, const u16* __restrict__ Vws,
    float* __restrict__ out)
{
    __shared__ __align__(16) u16 Vtlds[2][HD][KT + 8];  // 2 x 8.5 KB

    const int tid  = threadIdx.x;
    const int lane = tid & 63;
    const int wv   = tid >> 6;
    const int q15  = lane & 15;
    const int quad = lane >> 4;

    const int blk = blockIdx.x;        // 1024 blocks
    const int bh  = blk & 127;         // XCD swizzle: same bh -> same blk%8
    const int qt  = blk >> 7;
    const int b = bh >> 3, h = bh & 7;
    const int q0w = qt * 128 + wv * 32;  // wave's first query

    // ---- Q fragments: 2 x (16 rows x 32 d), fp32 global -> bf16 regs ----
    short8 qf[2];
    #pragma unroll
    for (int f = 0; f < 2; f++) {
        const float* qp = query + ((size_t)(b * S_ + q0w + f * 16 + q15)) * CC
                          + h * HD + quad * 8;
        float4 a = *(const float4*)(qp);
        float4 c = *(const float4*)(qp + 4);
        short8 v;
        v[0] = (short)f2bf(a.x); v[1] = (short)f2bf(a.y);
        v[2] = (short)f2bf(a.z); v[3] = (short)f2bf(a.w);
        v[4] = (short)f2bf(c.x); v[5] = (short)f2bf(c.y);
        v[6] = (short)f2bf(c.z); v[7] = (short)f2bf(c.w);
        qf[f] = v;
    }

    short8 ones;                       // bf16 1.0 = 0x3F80
    #pragma unroll
    for (int j = 0; j < 8; j++) ones[j] = (short)0x3F80;

    const u16* Kg = Kws + (size_t)bh * S_ * HD;
    const u16* Vg = Vws + (size_t)bh * S_ * HD;

    // ---- V staging geometry (fixed per thread) ----
    const int vg  = tid >> 3, vs4 = tid & 7;
    const int vc = vg >> 3, vw = vg & 7;
    const int vt2 = (vw >> 2) & 1, vqd = vw & 3;
    const int vpg = (vc << 5) | (vqd << 3) | (vt2 << 2);   // permuted col base

    uint2 vr0, vr1, vr2, vr3;          // V stage regs (32 B/thread)

    auto issue_v_loads = [&](int kt0) {
        const uint2* vsrc = (const uint2*)(Vg + (size_t)(kt0 + 4 * vg) * HD + 4 * vs4);
        vr0 = vsrc[0]; vr1 = vsrc[8]; vr2 = vsrc[16]; vr3 = vsrc[24];
    };
    auto write_lds = [&](int p) {
        u32 a, bb;
        a  = __builtin_amdgcn_perm(vr1.x, vr0.x, 0x05040100u);
        bb = __builtin_amdgcn_perm(vr3.x, vr2.x, 0x05040100u);
        *(uint2*)&Vtlds[p][4 * vs4 + 0][vpg] = make_uint2(a, bb);
        a  = __builtin_amdgcn_perm(vr1.x, vr0.x, 0x07060302u);
        bb = __builtin_amdgcn_perm(vr3.x, vr2.x, 0x07060302u);
        *(uint2*)&Vtlds[p][4 * vs4 + 1][vpg] = make_uint2(a, bb);
        a  = __builtin_amdgcn_perm(vr1.y, vr0.y, 0x05040100u);
        bb = __builtin_amdgcn_perm(vr3.y, vr2.y, 0x05040100u);
        *(uint2*)&Vtlds[p][4 * vs4 + 2][vpg] = make_uint2(a, bb);
        a  = __builtin_amdgcn_perm(vr1.y, vr0.y, 0x07060302u);
        bb = __builtin_amdgcn_perm(vr3.y, vr2.y, 0x07060302u);
        *(uint2*)&Vtlds[p][4 * vs4 + 3][vpg] = make_uint2(a, bb);
    };

    f32x4 Ot[2][2];                    // [frag][dhalf], C-layout (rows = d)
    f32x4 Dsum[2];                     // denominator accumulator
    #pragma unroll
    for (int f = 0; f < 2; f++) {
        Ot[f][0] = (f32x4)0.f; Ot[f][1] = (f32x4)0.f; Dsum[f] = (f32x4)0.f;
    }

    issue_v_loads(0);
    write_lds(0);                      // prologue: buffer 0

    for (int it = 0; it < NITER; it++) {
        const int p = it & 1;
        const int kt0 = it * KT;

        // ---- K fragments: direct global/L2, issued pre-barrier ----
        short8 kfr0[4], kfr1[4];
        #pragma unroll
        for (int c = 0; c < 4; c++) {
            kfr0[c] = *(const short8*)(Kg + (size_t)(kt0 + c * 32 + q15) * HD + quad * 8);
            kfr1[c] = *(const short8*)(Kg + (size_t)(kt0 + c * 32 + 16 + q15) * HD + quad * 8);
        }
        if (it + 1 < NITER) issue_v_loads((it + 1) * KT);  // next V tile in flight
        __syncthreads();               // buf p writes visible; prev readers of 1-p done

        // ---- chunk-fused: QK -> exp2 -> pack -> PV per 32 keys ----
        #pragma unroll
        for (int c = 0; c < 4; c++) {
            short8 vf0 = *(const short8*)&Vtlds[p][q15][c * 32 + quad * 8];
            short8 vf1 = *(const short8*)&Vtlds[p][16 + q15][c * 32 + quad * 8];
            #pragma unroll
            for (int f = 0; f < 2; f++) {
                f32x4 s0 = __builtin_amdgcn_mfma_f32_16x16x32_bf16(kfr0[c], qf[f], (f32x4)0.f, 0, 0, 0);
                f32x4 s1 = __builtin_amdgcn_mfma_f32_16x16x32_bf16(kfr1[c], qf[f], (f32x4)0.f, 0, 0, 0);
                #pragma unroll
                for (int r = 0; r < 4; r++) {
                    s0[r] = __builtin_amdgcn_exp2f(s0[r]);
                    s1[r] = __builtin_amdgcn_exp2f(s1[r]);
                }
                union { u32 u[4]; short8 s8; } pk;   // bf16-truncate pack
                pk.u[0] = __builtin_amdgcn_perm(__float_as_uint(s0[1]),
                                                __float_as_uint(s0[0]), 0x07060302u);
                pk.u[1] = __builtin_amdgcn_perm(__float_as_uint(s0[3]),
                                                __float_as_uint(s0[2]), 0x07060302u);
                pk.u[2] = __builtin_amdgcn_perm(__float_as_uint(s1[1]),
                                                __float_as_uint(s1[0]), 0x07060302u);
                pk.u[3] = __builtin_amdgcn_perm(__float_as_uint(s1[3]),
                                                __float_as_uint(s1[2]), 0x07060302u);
                Ot[f][0] = __builtin_amdgcn_mfma_f32_16x16x32_bf16(vf0, pk.s8, Ot[f][0], 0, 0, 0);
                Ot[f][1] = __builtin_amdgcn_mfma_f32_16x16x32_bf16(vf1, pk.s8, Ot[f][1], 0, 0, 0);
                Dsum[f]  = __builtin_amdgcn_mfma_f32_16x16x32_bf16(ones, pk.s8, Dsum[f], 0, 0, 0);
            }
        }
        if (it + 1 < NITER) write_lds((it + 1) & 1);      // idle buffer
    }

    // ---- epilogue: O^T[d][q] / Dsum[q] -> out[b][q][h*32+d] ----
    #pragma unroll
    for (int f = 0; f < 2; f++) {
        float inv = 1.0f / Dsum[f][0];
        int qg = q0w + f * 16 + q15;
        float* op = out + ((size_t)(b * S_ + qg)) * CC + h * HD;
        #pragma unroll
        for (int h2 = 0; h2 < 2; h2++)
            #pragma unroll
            for (int r = 0; r < 4; r++)
                op[h2 * 16 + quad * 4 + r] = Ot[f][h2][r] * inv;
    }
}

// ---------------------------------------------------------------------------
extern "C" void kernel_launch(void* const* d_in, const int* in_sizes, int n_in,
                              void* d_out, int out_size, void* d_ws, size_t ws_size,
                              hipStream_t stream)
{
    const float* query  = (const float*)d_in[0];
    const float* key_in = (const float*)d_in[1];
    const float* value  = (const float*)d_in[2];
    const float* ck     = (const float*)d_in[3];
    const float* cb     = (const float*)d_in[4];
    float* out = (float*)d_out;

    u16* Kws = (u16*)d_ws;                               // 8.39 MB
    u16* Vws = Kws + (size_t)B_ * HEADS * S_ * HD;       // 8.39 MB

    // LDS-staged conv: 2 tensors x 16 b x 4 y-tiles x 8 ch-groups = 1024 blocks.
    dw_conv_kernel<<<1024, 256, 0, stream>>>(
        key_in, value, ck, cb, Kws, Vws);

    // 128 queries per block (4 waves x 32): grid = 131072/128 = 1024 blocks.
    // blk decode is XCD-swizzled inside the kernel (bh = blk&127).
    attn_kernel<<<(B_ * HEADS * S_) / 128, 256, 0, stream>>>(
        query, Kws, Vws, out);
}

// Round 16
// 126.747 us; speedup vs baseline: 1.2757x; 1.0133x over previous
//
#include <hip/hip_runtime.h>

// DilatedSpatialAttention — round 16 (= R15 resubmitted; R15 hit
// GPUAcquisitionTimeout, bench never ran).
// Conv occupancy experiment: 32KB tile, 5 blocks/CU.
// DTYPES (established rounds 0-2): inputs fp32, output fp32.
// R14 (LDS-staged conv, 48KB tile): conv 34 -> ~28us. Banking audit: b128
// reads are at the 8-words/bank structural floor, so residual gap is not LDS.
// Remaining model: 48KB -> 3 blocks/CU = 12 waves/CU on a load-latency-bound
// kernel. R15/16: 4-row tiles (8 staged rows = 32KB exactly) -> 5 blocks/CU =
// 20 waves/CU, grid 2048. Halo amp 2.0x (+17MB, +2.7us traffic) is the price.
// Same bias-first (kh,kw)-ascending OOB-skip FMA order => conv bit-identical
// => absmax must stay exactly 1.220703e-4.
// Attn BYTE-IDENTICAL to R13/R14 (K direct from L2, V^T dbuf LDS, fixed-max
// log2-domain softmax, Dsum via mfma, XCD swizzle).
#define B_    16
#define HH    32
#define WW    32
#define CC    256
#define HEADS 8
#define HD    32
#define S_    1024
#define KT    128                 // keys per tile
#define NITER (S_ / KT)           // 8
#define SCALE_L2E 0.25503486f     // 32^-0.5 * log2(e)  (pre-folded into Kws)

typedef unsigned short u16;
typedef unsigned int   u32;
typedef __attribute__((ext_vector_type(8))) short short8;  // 8 bf16 (A/B frag)
typedef __attribute__((ext_vector_type(4))) float f32x4;   // C/D frag

__device__ __forceinline__ u16 f2bf(float f) {             // RNE
    u32 x = __float_as_uint(f);
    return (u16)((x + 0x7fffu + ((x >> 16) & 1u)) >> 16);
}
__device__ __forceinline__ u32 pack2bf(float lo, float hi) {
    return (u32)f2bf(lo) | ((u32)f2bf(hi) << 16);
}

// ---------------------------------------------------------------------------
// Kernel 1: depthwise dilated 3x3 (dil=2, SAME) conv, LDS-staged, 32KB tile.
// Block = (tensor t, batch b, y-tile of 4 rows, head-group g of 32 ch).
// LDS: 8 rows (y0-2..y0+5) x 32 x x 8 float4 = 32768 B -> 5 blocks/CU.
// Loads: 8 x 16B/thread coalesced. Compute: 4 outputs/thread, 9 LDS taps ea.
// Output head-major bf16 ws[(b*8+h)*1024+s][d]; K pre-scaled by SCALE_L2E.
// ---------------------------------------------------------------------------
__global__ __launch_bounds__(256) void dw_conv_kernel(
    const float* __restrict__ key_in, const float* __restrict__ value,
    const float* __restrict__ ck, const float* __restrict__ cb,
    u16* __restrict__ Kws, u16* __restrict__ Vws)
{
    __shared__ float4 tile[2048];      // [r 0..7][x 0..31][c 0..7]

    const int tid = threadIdx.x;
    const int blk = blockIdx.x;        // 2048 = 2 t x 16 b x 8 yt x 8 g
    const int g  = blk & 7;            // 32-ch head group (head h = g)
    const int yt = (blk >> 3) & 7;     // y tile (4 rows)
    const int b  = (blk >> 6) & 15;
    const int t  = blk >> 10;          // 0 = key, 1 = value (block-uniform)
    const float4* __restrict__ src4 = (const float4*)(t ? value : key_in);
    const int y0 = yt * 4;

    // ---- stage halo'd tile: 8 slots/thread, streaming coalesced ----
    #pragma unroll
    for (int i = 0; i < 8; i++) {
        int slot = tid + i * 256;      // slot = (r*32 + x)*8 + c
        int r = slot >> 8, x = (slot >> 3) & 31, cc = slot & 7;
        int yy = y0 - 2 + r;
        float4 v = make_float4(0.f, 0.f, 0.f, 0.f);
        if (yy >= 0 && yy < HH)
            v = src4[(((size_t)b * HH + yy) * WW + x) * 64 + g * 8 + cc];
        tile[slot] = v;
    }

    // ---- per-thread fixed channel quad c = tid&7: weights + bias once ----
    const int c = tid & 7;
    float4 w9[9];
    #pragma unroll
    for (int j = 0; j < 9; j++)
        w9[j] = *(const float4*)(ck + j * CC + g * 32 + c * 4);
    const float4 bias = *(const float4*)(cb + g * 32 + c * 4);

    __syncthreads();

    // ---- compute 4 outputs/thread from LDS (bias-first, kh/kw ascending,
    //      OOB-skip: identical FMA order to R14 -> bit-identical conv) ----
    #pragma unroll
    for (int i = 0; i < 4; i++) {
        int o = tid + i * 256;         // o = (ry*32 + x)*8 + c
        int x = (o >> 3) & 31, ry = o >> 8;
        float4 acc = bias;
        #pragma unroll
        for (int kh = 0; kh < 3; kh++) {
            #pragma unroll
            for (int kw = 0; kw < 3; kw++) {
                int xx = x - 2 + 2 * kw;
                if (xx < 0 || xx >= WW) continue;   // y-OOB rows are zero in LDS
                float4 v = tile[((ry + 2 * kh) * 32 + xx) * 8 + c];
                float4 w = w9[kh * 3 + kw];
                acc.x += w.x * v.x; acc.y += w.y * v.y;
                acc.z += w.z * v.z; acc.w += w.w * v.w;
            }
        }
        int spix = (y0 + ry) * WW + x;
        size_t off = (((size_t)(b * HEADS + g)) * S_ + spix) * HD + c * 4;
        if (t == 0)
            *(uint2*)&Kws[off] = make_uint2(pack2bf(acc.x * SCALE_L2E, acc.y * SCALE_L2E),
                                            pack2bf(acc.z * SCALE_L2E, acc.w * SCALE_L2E));
        else
            *(uint2*)&Vws[off] = make_uint2(pack2bf(acc.x, acc.y), pack2bf(acc.z, acc.w));
    }
}

// ---------------------------------------------------------------------------
// Kernel 2: MFMA flash attention (BYTE-IDENTICAL to R13/R14). K-fragments
// direct from global/L2 (Kws[key][d] == A-frag layout), issued pre-barrier.
// V^T double-buffered in LDS with per-32-chunk column permutation
// pos(Q,t',r) <- key(t',Q,r). Fixed-max softmax in log2 domain; denominator
// via mfma(ones, pk, Dsum). bh = blk&127 XCD swizzle.
// ---------------------------------------------------------------------------
__global__ __launch_bounds__(256, 4) void attn_kernel(
    const float* __restrict__ query,
    const u16* __restrict__ Kws, const u16* __restrict__ Vws,
    float* __restrict__ out)
{
    __shared__ __align__(16) u16 Vtlds[2][HD][KT + 8];  // 2 x 8.5 KB

    const int tid  = threadIdx.x;
    const int lane = tid & 63;
    const int wv   = tid >> 6;
    const int q15  = lane & 15;
    const int quad = lane >> 4;

    const int blk = blockIdx.x;        // 1024 blocks
    const int bh  = blk & 127;         // XCD swizzle: same bh -> same blk%8
    const int qt  = blk >> 7;
    const int b = bh >> 3, h = bh & 7;
    const int q0w = qt * 128 + wv * 32;  // wave's first query

    // ---- Q fragments: 2 x (16 rows x 32 d), fp32 global -> bf16 regs ----
    short8 qf[2];
    #pragma unroll
    for (int f = 0; f < 2; f++) {
        const float* qp = query + ((size_t)(b * S_ + q0w + f * 16 + q15)) * CC
                          + h * HD + quad * 8;
        float4 a = *(const float4*)(qp);
        float4 c = *(const float4*)(qp + 4);
        short8 v;
        v[0] = (short)f2bf(a.x); v[1] = (short)f2bf(a.y);
        v[2] = (short)f2bf(a.z); v[3] = (short)f2bf(a.w);
        v[4] = (short)f2bf(c.x); v[5] = (short)f2bf(c.y);
        v[6] = (short)f2bf(c.z); v[7] = (short)f2bf(c.w);
        qf[f] = v;
    }

    short8 ones;                       // bf16 1.0 = 0x3F80
    #pragma unroll
    for (int j = 0; j < 8; j++) ones[j] = (short)0x3F80;

    const u16* Kg = Kws + (size_t)bh * S_ * HD;
    const u16* Vg = Vws + (size_t)bh * S_ * HD;

    // ---- V staging geometry (fixed per thread) ----
    const int vg  = tid >> 3, vs4 = tid & 7;
    const int vc = vg >> 3, vw = vg & 7;
    const int vt2 = (vw >> 2) & 1, vqd = vw & 3;
    const int vpg = (vc << 5) | (vqd << 3) | (vt2 << 2);   // permuted col base

    uint2 vr0, vr1, vr2, vr3;          // V stage regs (32 B/thread)

    auto issue_v_loads = [&](int kt0) {
        const uint2* vsrc = (const uint2*)(Vg + (size_t)(kt0 + 4 * vg) * HD + 4 * vs4);
        vr0 = vsrc[0]; vr1 = vsrc[8]; vr2 = vsrc[16]; vr3 = vsrc[24];
    };
    auto write_lds = [&](int p) {
        u32 a, bb;
        a  = __builtin_amdgcn_perm(vr1.x, vr0.x, 0x05040100u);
        bb = __builtin_amdgcn_perm(vr3.x, vr2.x, 0x05040100u);
        *(uint2*)&Vtlds[p][4 * vs4 + 0][vpg] = make_uint2(a, bb);
        a  = __builtin_amdgcn_perm(vr1.x, vr0.x, 0x07060302u);
        bb = __builtin_amdgcn_perm(vr3.x, vr2.x, 0x07060302u);
        *(uint2*)&Vtlds[p][4 * vs4 + 1][vpg] = make_uint2(a, bb);
        a  = __builtin_amdgcn_perm(vr1.y, vr0.y, 0x05040100u);
        bb = __builtin_amdgcn_perm(vr3.y, vr2.y, 0x05040100u);
        *(uint2*)&Vtlds[p][4 * vs4 + 2][vpg] = make_uint2(a, bb);
        a  = __builtin_amdgcn_perm(vr1.y, vr0.y, 0x07060302u);
        bb = __builtin_amdgcn_perm(vr3.y, vr2.y, 0x07060302u);
        *(uint2*)&Vtlds[p][4 * vs4 + 3][vpg] = make_uint2(a, bb);
    };

    f32x4 Ot[2][2];                    // [frag][dhalf], C-layout (rows = d)
    f32x4 Dsum[2];                     // denominator accumulator
    #pragma unroll
    for (int f = 0; f < 2; f++) {
        Ot[f][0] = (f32x4)0.f; Ot[f][1] = (f32x4)0.f; Dsum[f] = (f32x4)0.f;
    }

    issue_v_loads(0);
    write_lds(0);                      // prologue: buffer 0

    for (int it = 0; it < NITER; it++) {
        const int p = it & 1;
        const int kt0 = it * KT;

        // ---- K fragments: direct global/L2, issued pre-barrier ----
        short8 kfr0[4], kfr1[4];
        #pragma unroll
        for (int c = 0; c < 4; c++) {
            kfr0[c] = *(const short8*)(Kg + (size_t)(kt0 + c * 32 + q15) * HD + quad * 8);
            kfr1[c] = *(const short8*)(Kg + (size_t)(kt0 + c * 32 + 16 + q15) * HD + quad * 8);
        }
        if (it + 1 < NITER) issue_v_loads((it + 1) * KT);  // next V tile in flight
        __syncthreads();               // buf p writes visible; prev readers of 1-p done

        // ---- chunk-fused: QK -> exp2 -> pack -> PV per 32 keys ----
        #pragma unroll
        for (int c = 0; c < 4; c++) {
            short8 vf0 = *(const short8*)&Vtlds[p][q15][c * 32 + quad * 8];
            short8 vf1 = *(const short8*)&Vtlds[p][16 + q15][c * 32 + quad * 8];
            #pragma unroll
            for (int f = 0; f < 2; f++) {
                f32x4 s0 = __builtin_amdgcn_mfma_f32_16x16x32_bf16(kfr0[c], qf[f], (f32x4)0.f, 0, 0, 0);
                f32x4 s1 = __builtin_amdgcn_mfma_f32_16x16x32_bf16(kfr1[c], qf[f], (f32x4)0.f, 0, 0, 0);
                #pragma unroll
                for (int r = 0; r < 4; r++) {
                    s0[r] = __builtin_amdgcn_exp2f(s0[r]);
                    s1[r] = __builtin_amdgcn_exp2f(s1[r]);
                }
                union { u32 u[4]; short8 s8; } pk;   // bf16-truncate pack
                pk.u[0] = __builtin_amdgcn_perm(__float_as_uint(s0[1]),
                                                __float_as_uint(s0[0]), 0x07060302u);
                pk.u[1] = __builtin_amdgcn_perm(__float_as_uint(s0[3]),
                                                __float_as_uint(s0[2]), 0x07060302u);
                pk.u[2] = __builtin_amdgcn_perm(__float_as_uint(s1[1]),
                                                __float_as_uint(s1[0]), 0x07060302u);
                pk.u[3] = __builtin_amdgcn_perm(__float_as_uint(s1[3]),
                                                __float_as_uint(s1[2]), 0x07060302u);
                Ot[f][0] = __builtin_amdgcn_mfma_f32_16x16x32_bf16(vf0, pk.s8, Ot[f][0], 0, 0, 0);
                Ot[f][1] = __builtin_amdgcn_mfma_f32_16x16x32_bf16(vf1, pk.s8, Ot[f][1], 0, 0, 0);
                Dsum[f]  = __builtin_amdgcn_mfma_f32_16x16x32_bf16(ones, pk.s8, Dsum[f], 0, 0, 0);
            }
        }
        if (it + 1 < NITER) write_lds((it + 1) & 1);      // idle buffer
    }

    // ---- epilogue: O^T[d][q] / Dsum[q] -> out[b][q][h*32+d] ----
    #pragma unroll
    for (int f = 0; f < 2; f++) {
        float inv = 1.0f / Dsum[f][0];
        int qg = q0w + f * 16 + q15;
        float* op = out + ((size_t)(b * S_ + qg)) * CC + h * HD;
        #pragma unroll
        for (int h2 = 0; h2 < 2; h2++)
            #pragma unroll
            for (int r = 0; r < 4; r++)
                op[h2 * 16 + quad * 4 + r] = Ot[f][h2][r] * inv;
    }
}

// ---------------------------------------------------------------------------
extern "C" void kernel_launch(void* const* d_in, const int* in_sizes, int n_in,
                              void* d_out, int out_size, void* d_ws, size_t ws_size,
                              hipStream_t stream)
{
    const float* query  = (const float*)d_in[0];
    const float* key_in = (const float*)d_in[1];
    const float* value  = (const float*)d_in[2];
    const float* ck     = (const float*)d_in[3];
    const float* cb     = (const float*)d_in[4];
    float* out = (float*)d_out;

    u16* Kws = (u16*)d_ws;                               // 8.39 MB
    u16* Vws = Kws + (size_t)B_ * HEADS * S_ * HD;       // 8.39 MB

    // LDS-staged conv: 2 t x 16 b x 8 y-tiles x 8 ch-groups = 2048 blocks.
    dw_conv_kernel<<<2048, 256, 0, stream>>>(
        key_in, value, ck, cb, Kws, Vws);

    // 128 queries per block (4 waves x 32): grid = 131072/128 = 1024 blocks.
    // blk decode is XCD-swizzled inside the kernel (bh = blk&127).
    attn_kernel<<<(B_ * HEADS * S_) / 128, 256, 0, stream>>>(
        query, Kws, Vws, out);
}